// Round 1
// baseline (570.480 us; speedup 1.0000x reference)
//
#include <hip/hip_runtime.h>
#include <math.h>

#ifndef M_PI
#define M_PI 3.14159265358979323846
#endif

constexpr int S_LEN   = 176400;
constexpr int NFFT    = 2048;
constexpr int NC      = 1024;   // complex FFT length (real-fft trick)
constexpr int HOP_    = 441;
constexpr int T_FRAMES = 401;
constexpr int F_BINS  = 1025;
constexpr int N_CH    = 64;     // B*C = 32*2
constexpr float EPS_  = 1e-8f;
constexpr float C1_   = 0.0004f;   // (0.01*2)^2
constexpr float C2_   = 0.0036f;   // (0.03*2)^2
constexpr float COV_NORM_ = 49.0f / 48.0f;

__global__ void zero_out_kernel(float* out) {
    out[threadIdx.x] = 0.0f;
}

// One block per (frame t, channel-in-group, which input).
// Real 2048-pt FFT via 1024-pt complex Stockham radix-2 in LDS.
__global__ __launch_bounds__(256) void stft_mag_kernel(
    const float* __restrict__ x0, const float* __restrict__ x1,
    float* __restrict__ spec, int ch0, int nch)
{
    __shared__ float2 bufA[NC];
    __shared__ float2 bufB[NC];
    __shared__ float2 tw[NC / 2];

    const int tid   = threadIdx.x;
    const int t     = blockIdx.x;
    const int cg    = blockIdx.y;
    const int which = blockIdx.z;     // 0 = output, 1 = target
    const int ch    = ch0 + cg;

    const float* __restrict__ xin =
        (which == 0 ? x0 : x1) + (size_t)ch * S_LEN;
    float* __restrict__ sout =
        spec + ((size_t)which * nch + cg) * (size_t)T_FRAMES * F_BINS
             + (size_t)t * F_BINS;

    // twiddle table: tw[p] = exp(-2*pi*i * p / 1024), p in [0, 512)
    for (int p = tid; p < NC / 2; p += 256) {
        float ang = -2.0f * (float)M_PI * (float)p / (float)NC;
        float s, c;
        sincosf(ang, &s, &c);
        tw[p] = make_float2(c, s);
    }

    // load frame (reflect pad), window, pack even/odd into complex
    const int base = t * HOP_ - NFFT / 2;
    float* bufAf = (float*)bufA;    // flat float index n -> complex n/2, comp n&1
    for (int k = 0; k < NFFT / 256; ++k) {
        int n = k * 256 + tid;
        int j = base + n;
        j = (j < 0) ? -j : j;
        j = (j >= S_LEN) ? (2 * S_LEN - 2 - j) : j;
        float w = 0.5f - 0.5f * cosf((float)(2.0 * M_PI / NFFT) * (float)n);
        bufAf[n] = xin[j] * w;
    }
    __syncthreads();

    // 10-stage Stockham radix-2 DIF (autosorting). Even stage count -> result in bufA.
    {
        float2* A = bufA;
        float2* B = bufB;
        for (int i = 0; i < 10; ++i) {
            const int s_ = 1 << i;
            for (int bb = tid; bb < 512; bb += 256) {
                const int q  = bb & (s_ - 1);
                const int p  = bb >> i;
                const int i0 = q + (p << i);
                const int i1 = i0 + 512;
                float2 a = A[i0];
                float2 b = A[i1];
                float2 wp = tw[p << i];
                float2 sum = make_float2(a.x + b.x, a.y + b.y);
                float dx = a.x - b.x;
                float dy = a.y - b.y;
                float2 prod = make_float2(dx * wp.x - dy * wp.y,
                                          dx * wp.y + dy * wp.x);
                const int o0 = q + (p << (i + 1));
                B[o0]      = sum;
                B[o0 + s_] = prod;
            }
            __syncthreads();
            float2* tmp = A; A = B; B = tmp;
        }
    }

    // unpack real-FFT bins r in [0, 1024], magnitude, store
    for (int r = tid; r < F_BINS; r += 256) {
        float2 Zr = bufA[r & (NC - 1)];
        float2 Zn = bufA[(NC - r) & (NC - 1)];
        // E = (Zr + conj(Zn))/2 ; O = -i/2 * (Zr - conj(Zn))
        float Ex = 0.5f * (Zr.x + Zn.x);
        float Ey = 0.5f * (Zr.y - Zn.y);
        float Ox = 0.5f * (Zr.y + Zn.y);
        float Oy = 0.5f * (Zn.x - Zr.x);
        float ang = -(float)M_PI * (float)r / (float)NC;
        float sw, cw;
        sincosf(ang, &sw, &cw);
        float Xx = Ex + cw * Ox - sw * Oy;
        float Xy = Ey + cw * Oy + sw * Ox;
        float m2 = Xx * Xx + Xy * Xy;
        sout[r] = sqrtf(fmaxf(m2, EPS_));
    }
}

// SSIM over interior (crop removes all pad-touching pixels -> pure valid-mode 7x7).
// Block per (channel-in-group, chunk of output rows). Per row: column 7-sums into
// LDS, then 7-tap horizontal window + SSIM formula; fp64 accumulate.
__global__ __launch_bounds__(256) void ssim_kernel(
    const float* __restrict__ spec, float* __restrict__ out,
    int ch0, int nch, int rows_per_block)
{
    __shared__ float csx[F_BINS], csy[F_BINS], csxx[F_BINS], csyy[F_BINS], csxy[F_BINS];
    __shared__ double red[256];

    const int tid = threadIdx.x;
    const int cg  = blockIdx.y;
    const int ch  = ch0 + cg;
    const float* __restrict__ X = spec + (size_t)cg * (size_t)T_FRAMES * F_BINS;
    const float* __restrict__ Y = spec + ((size_t)nch + cg) * (size_t)T_FRAMES * F_BINS;

    const int t_begin = 3 + blockIdx.x * rows_per_block;
    const int t_end_  = min(t_begin + rows_per_block, T_FRAMES - 3); // exclusive; rows [3, 397]

    const float inv49 = 1.0f / 49.0f;
    double acc = 0.0;

    for (int t = t_begin; t < t_end_; ++t) {
        for (int f = tid; f < F_BINS; f += 256) {
            float sx = 0.f, sy = 0.f, sxx = 0.f, syy = 0.f, sxy = 0.f;
            #pragma unroll
            for (int dt = -3; dt <= 3; ++dt) {
                float xv = X[(size_t)(t + dt) * F_BINS + f];
                float yv = Y[(size_t)(t + dt) * F_BINS + f];
                sx += xv; sy += yv;
                sxx += xv * xv; syy += yv * yv; sxy += xv * yv;
            }
            csx[f] = sx; csy[f] = sy; csxx[f] = sxx; csyy[f] = syy; csxy[f] = sxy;
        }
        __syncthreads();

        for (int f = 3 + tid; f <= F_BINS - 4; f += 256) {   // cols [3, 1021]
            float wx = 0.f, wy = 0.f, wxx = 0.f, wyy = 0.f, wxy = 0.f;
            #pragma unroll
            for (int df = -3; df <= 3; ++df) {
                wx  += csx[f + df];
                wy  += csy[f + df];
                wxx += csxx[f + df];
                wyy += csyy[f + df];
                wxy += csxy[f + df];
            }
            float ux  = wx  * inv49, uy  = wy  * inv49;
            float uxx = wxx * inv49, uyy = wyy * inv49, uxy = wxy * inv49;
            float vx  = COV_NORM_ * (uxx - ux * ux);
            float vy  = COV_NORM_ * (uyy - uy * uy);
            float vxy = COV_NORM_ * (uxy - ux * uy);
            float Sv = ((2.f * ux * uy + C1_) * (2.f * vxy + C2_)) /
                       ((ux * ux + uy * uy + C1_) * (vx + vy + C2_));
            acc += (double)Sv;
        }
        __syncthreads();
    }

    red[tid] = acc;
    __syncthreads();
    for (int off = 128; off > 0; off >>= 1) {
        if (tid < off) red[tid] += red[tid + off];
        __syncthreads();
    }
    if (tid == 0) {
        atomicAdd(&out[ch], (float)(red[0] / (395.0 * 1019.0)));
    }
}

extern "C" void kernel_launch(void* const* d_in, const int* in_sizes, int n_in,
                              void* d_out, int out_size, void* d_ws, size_t ws_size,
                              hipStream_t stream) {
    const float* x0 = (const float*)d_in[0];   // output
    const float* x1 = (const float*)d_in[1];   // target
    float* out = (float*)d_out;
    float* ws  = (float*)d_ws;

    // workspace holds both spectrograms for a group of channels
    const size_t per_ch_bytes = (size_t)2 * T_FRAMES * F_BINS * sizeof(float);
    int G = (int)(ws_size / per_ch_bytes);
    if (G > N_CH) G = N_CH;
    if (G < 1)    G = 1;

    zero_out_kernel<<<dim3(1), dim3(64), 0, stream>>>(out);

    for (int ch0 = 0; ch0 < N_CH; ch0 += G) {
        const int nch = (N_CH - ch0 < G) ? (N_CH - ch0) : G;

        dim3 g1(T_FRAMES, nch, 2);
        stft_mag_kernel<<<g1, 256, 0, stream>>>(x0, x1, ws, ch0, nch);

        const int rows = T_FRAMES - 6;         // 395 output rows
        const int rpb  = 32;
        const int chunks = (rows + rpb - 1) / rpb;
        dim3 g2(chunks, nch);
        ssim_kernel<<<g2, 256, 0, stream>>>(ws, out, ch0, nch, rpb);
    }
}

// Round 2
// 430.316 us; speedup vs baseline: 1.3257x; 1.3257x over previous
//
#include <hip/hip_runtime.h>
#include <math.h>

#ifndef M_PI
#define M_PI 3.14159265358979323846
#endif

constexpr int S_LEN   = 176400;
constexpr int NFFT    = 2048;
constexpr int NC      = 1024;   // complex FFT length (real-fft trick)
constexpr int HOP_    = 441;
constexpr int T_FRAMES = 401;
constexpr int F_BINS  = 1025;
constexpr int N_CH    = 64;     // B*C = 32*2
constexpr float EPS_  = 1e-8f;
constexpr float C1_   = 0.0004f;   // (0.01*2)^2
constexpr float C2_   = 0.0036f;   // (0.03*2)^2
constexpr float COV_NORM_ = 49.0f / 48.0f;

// workspace layout (floats): [win 2048][tw 768*2][utw 1025*2 (+pad)] then spec
constexpr int WIN_OFF  = 0;
constexpr int TW_OFF   = 2048;          // float2[768] -> 1536 floats
constexpr int UTW_OFF  = 2048 + 1536;   // float2[1025] -> 2050 floats
constexpr int SPEC_OFF = 5696;          // padded to 256B multiple
constexpr int RPB_     = 25;            // ssim rows per block
constexpr int N_CHUNKS = 16;            // ceil(395/25)

__device__ __forceinline__ int phys(int i) { return i + (i >> 4); }

__global__ void zero_out_kernel(float* out) {
    out[threadIdx.x] = 0.0f;
}

// Precompute window + FFT twiddles + real-unpack twiddles into workspace.
__global__ __launch_bounds__(256) void init_tables_kernel(float* __restrict__ ws) {
    const int idx = blockIdx.x * 256 + threadIdx.x;
    // hann window (periodic)
    if (idx < NFFT) {
        ws[WIN_OFF + idx] = 0.5f - 0.5f * cosf((float)(2.0 * M_PI / NFFT) * (float)idx);
    }
    // stage twiddles: tw[e] = exp(-2*pi*i*e/1024), e in [0,768)
    if (idx < 768) {
        float ang = -2.0f * (float)M_PI * (float)idx / (float)NC;
        float s, c;
        sincosf(ang, &s, &c);
        ws[TW_OFF + 2 * idx]     = c;
        ws[TW_OFF + 2 * idx + 1] = s;
    }
    // unpack twiddles: utw[r] = exp(-i*pi*r/1024), r in [0,1025)
    if (idx < F_BINS) {
        float ang = -(float)M_PI * (float)idx / (float)NC;
        float s, c;
        sincosf(ang, &s, &c);
        ws[UTW_OFF + 2 * idx]     = c;
        ws[UTW_OFF + 2 * idx + 1] = s;
    }
}

// One block per (frame t, channel-in-group, which input).
// Real 2048-pt FFT via 1024-pt complex radix-4 Stockham (5 stages) in LDS.
__global__ __launch_bounds__(256) void stft_mag_kernel(
    const float* __restrict__ x0, const float* __restrict__ x1,
    float* __restrict__ ws, int ch0, int nch)
{
    __shared__ float2 bufA[NC + NC / 16];
    __shared__ float2 bufB[NC + NC / 16];
    __shared__ float2 tw_s[768];

    const int tid   = threadIdx.x;
    const int t     = blockIdx.x;
    const int cg    = blockIdx.y;
    const int which = blockIdx.z;     // 0 = output, 1 = target
    const int ch    = ch0 + cg;

    const float* __restrict__ xin =
        (which == 0 ? x0 : x1) + (size_t)ch * S_LEN;
    const float* __restrict__ win = ws + WIN_OFF;
    const float2* __restrict__ twg = (const float2*)(ws + TW_OFF);
    const float2* __restrict__ utw = (const float2*)(ws + UTW_OFF);
    float* __restrict__ sout =
        ws + SPEC_OFF
           + ((size_t)which * nch + cg) * (size_t)T_FRAMES * F_BINS
           + (size_t)t * F_BINS;

    // load stage twiddles into LDS (3 per thread, coalesced)
    #pragma unroll
    for (int k = 0; k < 3; ++k) {
        int p = k * 256 + tid;
        tw_s[p] = twg[p];
    }

    // load frame (reflect pad), window, pack even/odd into complex (padded layout)
    const int base = t * HOP_ - NFFT / 2;
    float* bufAf = (float*)bufA;
    #pragma unroll
    for (int k = 0; k < NFFT / 256; ++k) {
        int n = k * 256 + tid;
        int j = base + n;
        j = (j < 0) ? -j : j;
        j = (j >= S_LEN) ? (2 * S_LEN - 2 - j) : j;
        float v = xin[j] * win[n];
        int ci = n >> 1;
        bufAf[(n & 1) + 2 * phys(ci)] = v;
    }
    __syncthreads();

    // 5-stage radix-4 Stockham DIF (autosorting)
    float2* A = bufA;
    float2* B = bufB;
    #pragma unroll
    for (int i = 0; i < 5; ++i) {
        const int s_ = 1 << (2 * i);
        const int b  = tid;
        const int q  = b & (s_ - 1);
        const int ps = b - q;            // p * s

        float2 x0c = A[phys(b)];
        float2 x1c = A[phys(b + 256)];
        float2 x2c = A[phys(b + 512)];
        float2 x3c = A[phys(b + 768)];

        float2 t0 = make_float2(x0c.x + x2c.x, x0c.y + x2c.y);
        float2 t1 = make_float2(x0c.x - x2c.x, x0c.y - x2c.y);
        float2 t2 = make_float2(x1c.x + x3c.x, x1c.y + x3c.y);
        float2 t3 = make_float2(x1c.x - x3c.x, x1c.y - x3c.y);

        float2 y0 = make_float2(t0.x + t2.x, t0.y + t2.y);
        float2 y2 = make_float2(t0.x - t2.x, t0.y - t2.y);
        float2 y1 = make_float2(t1.x + t3.y, t1.y - t3.x);   // t1 - i*t3
        float2 y3 = make_float2(t1.x - t3.y, t1.y + t3.x);   // t1 + i*t3

        float2 w1 = tw_s[ps];
        float2 w2 = tw_s[2 * ps];
        float2 w3 = tw_s[3 * ps];

        float2 z1 = make_float2(y1.x * w1.x - y1.y * w1.y, y1.x * w1.y + y1.y * w1.x);
        float2 z2 = make_float2(y2.x * w2.x - y2.y * w2.y, y2.x * w2.y + y2.y * w2.x);
        float2 z3 = make_float2(y3.x * w3.x - y3.y * w3.y, y3.x * w3.y + y3.y * w3.x);

        const int o = q + 4 * ps;        // q + 4*s*p
        B[phys(o)]          = y0;
        B[phys(o + s_)]     = z1;
        B[phys(o + 2 * s_)] = z2;
        B[phys(o + 3 * s_)] = z3;
        __syncthreads();
        float2* tmp = A; A = B; B = tmp;
    }
    // result now in A (after final swap)

    // unpack real-FFT bins r in [0, 1024], magnitude, store
    for (int r = tid; r < F_BINS; r += 256) {
        float2 Zr = A[phys(r & (NC - 1))];
        float2 Zn = A[phys((NC - r) & (NC - 1))];
        float Ex = 0.5f * (Zr.x + Zn.x);
        float Ey = 0.5f * (Zr.y - Zn.y);
        float Ox = 0.5f * (Zr.y + Zn.y);
        float Oy = 0.5f * (Zn.x - Zr.x);
        float2 wu = utw[r];
        float Xx = Ex + wu.x * Ox - wu.y * Oy;
        float Xy = Ey + wu.x * Oy + wu.y * Ox;
        float m2 = Xx * Xx + Xy * Xy;
        sout[r] = sqrtf(fmaxf(m2, EPS_));
    }
}

// SSIM over interior (crop removes all pad-touching pixels -> pure valid-mode 7x7).
// Rolling vertical column sums in registers; horizontal 7-tap via packed LDS.
__global__ __launch_bounds__(256) void ssim_kernel(
    const float* __restrict__ ws, float* __restrict__ out,
    int ch0, int nch)
{
    __shared__ float4 cs4[F_BINS];   // (sx, sy, sxx, syy)
    __shared__ float  cs1[F_BINS];   // sxy
    __shared__ double red[256];

    const int tid = threadIdx.x;
    const int cg  = blockIdx.y;
    const int ch  = ch0 + cg;
    const float* __restrict__ spec = ws + SPEC_OFF;
    const float* __restrict__ X = spec + (size_t)cg * (size_t)T_FRAMES * F_BINS;
    const float* __restrict__ Y = spec + ((size_t)nch + cg) * (size_t)T_FRAMES * F_BINS;

    const int t_begin = 3 + blockIdx.x * RPB_;
    const int t_end_  = min(t_begin + RPB_, T_FRAMES - 3); // rows [3, 397]

    const float inv49 = 1.0f / 49.0f;
    double acc = 0.0;

    // rolling register sums for owned columns f = tid + 256k
    float sx[5], sy[5], sxx[5], syy[5], sxy[5];
    #pragma unroll
    for (int k = 0; k < 5; ++k) { sx[k]=0.f; sy[k]=0.f; sxx[k]=0.f; syy[k]=0.f; sxy[k]=0.f; }

    // init with rows [t_begin-3, t_begin+2]
    for (int r = t_begin - 3; r < t_begin + 3; ++r) {
        #pragma unroll
        for (int k = 0; k < 5; ++k) {
            int f = tid + (k << 8);
            if (f < F_BINS) {
                float xv = X[(size_t)r * F_BINS + f];
                float yv = Y[(size_t)r * F_BINS + f];
                sx[k] += xv; sy[k] += yv;
                sxx[k] += xv * xv; syy[k] += yv * yv; sxy[k] += xv * yv;
            }
        }
    }

    for (int t = t_begin; t < t_end_; ++t) {
        // add row t+3, publish sums
        #pragma unroll
        for (int k = 0; k < 5; ++k) {
            int f = tid + (k << 8);
            if (f < F_BINS) {
                float xv = X[(size_t)(t + 3) * F_BINS + f];
                float yv = Y[(size_t)(t + 3) * F_BINS + f];
                sx[k] += xv; sy[k] += yv;
                sxx[k] += xv * xv; syy[k] += yv * yv; sxy[k] += xv * yv;
                cs4[f] = make_float4(sx[k], sy[k], sxx[k], syy[k]);
                cs1[f] = sxy[k];
            }
        }
        __syncthreads();

        // horizontal 7-tap + SSIM formula, cols [3, 1021]
        for (int f = 3 + tid; f <= F_BINS - 4; f += 256) {
            float4 a0 = cs4[f - 3], a1 = cs4[f - 2], a2 = cs4[f - 1], a3 = cs4[f];
            float4 a4 = cs4[f + 1], a5 = cs4[f + 2], a6 = cs4[f + 3];
            float wx  = a0.x + a1.x + a2.x + a3.x + a4.x + a5.x + a6.x;
            float wy  = a0.y + a1.y + a2.y + a3.y + a4.y + a5.y + a6.y;
            float wxx = a0.z + a1.z + a2.z + a3.z + a4.z + a5.z + a6.z;
            float wyy = a0.w + a1.w + a2.w + a3.w + a4.w + a5.w + a6.w;
            float wxy = cs1[f-3] + cs1[f-2] + cs1[f-1] + cs1[f] + cs1[f+1] + cs1[f+2] + cs1[f+3];

            float ux  = wx  * inv49, uy  = wy  * inv49;
            float uxx = wxx * inv49, uyy = wyy * inv49, uxy = wxy * inv49;
            float vx  = COV_NORM_ * (uxx - ux * ux);
            float vy  = COV_NORM_ * (uyy - uy * uy);
            float vxy = COV_NORM_ * (uxy - ux * uy);
            float Sv = ((2.f * ux * uy + C1_) * (2.f * vxy + C2_)) /
                       ((ux * ux + uy * uy + C1_) * (vx + vy + C2_));
            acc += (double)Sv;
        }
        __syncthreads();

        // subtract row t-3
        #pragma unroll
        for (int k = 0; k < 5; ++k) {
            int f = tid + (k << 8);
            if (f < F_BINS) {
                float xv = X[(size_t)(t - 3) * F_BINS + f];
                float yv = Y[(size_t)(t - 3) * F_BINS + f];
                sx[k] -= xv; sy[k] -= yv;
                sxx[k] -= xv * xv; syy[k] -= yv * yv; sxy[k] -= xv * yv;
            }
        }
    }

    red[tid] = acc;
    __syncthreads();
    for (int off = 128; off > 0; off >>= 1) {
        if (tid < off) red[tid] += red[tid + off];
        __syncthreads();
    }
    if (tid == 0) {
        atomicAdd(&out[ch], (float)(red[0] / (395.0 * 1019.0)));
    }
}

extern "C" void kernel_launch(void* const* d_in, const int* in_sizes, int n_in,
                              void* d_out, int out_size, void* d_ws, size_t ws_size,
                              hipStream_t stream) {
    const float* x0 = (const float*)d_in[0];   // output
    const float* x1 = (const float*)d_in[1];   // target
    float* out = (float*)d_out;
    float* ws  = (float*)d_ws;

    const size_t table_bytes  = (size_t)SPEC_OFF * sizeof(float);
    const size_t per_ch_bytes = (size_t)2 * T_FRAMES * F_BINS * sizeof(float);
    int G = (int)((ws_size - table_bytes) / per_ch_bytes);
    if (G > N_CH) G = N_CH;
    if (G < 1)    G = 1;

    zero_out_kernel<<<dim3(1), dim3(64), 0, stream>>>(out);
    init_tables_kernel<<<dim3(8), dim3(256), 0, stream>>>(ws);

    for (int ch0 = 0; ch0 < N_CH; ch0 += G) {
        const int nch = (N_CH - ch0 < G) ? (N_CH - ch0) : G;

        dim3 g1(T_FRAMES, nch, 2);
        stft_mag_kernel<<<g1, 256, 0, stream>>>(x0, x1, ws, ch0, nch);

        dim3 g2(N_CHUNKS, nch);
        ssim_kernel<<<g2, 256, 0, stream>>>(ws, out, ch0, nch);
    }
}

// Round 3
// 411.807 us; speedup vs baseline: 1.3853x; 1.0449x over previous
//
#include <hip/hip_runtime.h>
#include <math.h>

#ifndef M_PI
#define M_PI 3.14159265358979323846
#endif

constexpr int S_LEN   = 176400;
constexpr int NFFT    = 2048;
constexpr int NC      = 1024;   // complex FFT length (real-fft trick)
constexpr int HOP_    = 441;
constexpr int T_FRAMES = 401;
constexpr int F_BINS  = 1025;
constexpr int N_CH    = 64;     // B*C = 32*2
constexpr float EPS_  = 1e-8f;
constexpr float C1_   = 0.0004f;   // (0.01*2)^2
constexpr float C2_   = 0.0036f;   // (0.03*2)^2
constexpr float COV_NORM_ = 49.0f / 48.0f;

// workspace layout (floats): [win 2048][tw 768*2][utw 1025*2 (+pad)] then spec
constexpr int WIN_OFF  = 0;
constexpr int TW_OFF   = 2048;          // float2[768] -> 1536 floats
constexpr int UTW_OFF  = 2048 + 1536;   // float2[1025] -> 2050 floats
constexpr int SPEC_OFF = 5696;          // padded to 256B multiple
constexpr int RPB_     = 10;            // ssim rows per block
constexpr int N_CHUNKS = 40;            // ceil(395/10)

// pad every 4 complex: per-wave conflict-free for all radix-4 stage strides
__device__ __forceinline__ int phys(int i) { return i + (i >> 2); }
constexpr int BUF_SZ = 1280;            // phys(1023)=1278

__global__ void zero_out_kernel(float* out) {
    out[threadIdx.x] = 0.0f;
}

// Precompute window + FFT twiddles + real-unpack twiddles into workspace.
__global__ __launch_bounds__(256) void init_tables_kernel(float* __restrict__ ws) {
    const int idx = blockIdx.x * 256 + threadIdx.x;
    if (idx < NFFT) {
        ws[WIN_OFF + idx] = 0.5f - 0.5f * cosf((float)(2.0 * M_PI / NFFT) * (float)idx);
    }
    if (idx < 768) {
        float ang = -2.0f * (float)M_PI * (float)idx / (float)NC;
        float s, c;
        sincosf(ang, &s, &c);
        ws[TW_OFF + 2 * idx]     = c;
        ws[TW_OFF + 2 * idx + 1] = s;
    }
    if (idx < F_BINS) {
        float ang = -(float)M_PI * (float)idx / (float)NC;
        float s, c;
        sincosf(ang, &s, &c);
        ws[UTW_OFF + 2 * idx]     = c;
        ws[UTW_OFF + 2 * idx + 1] = s;
    }
}

// One block per (frame t, channel): BOTH inputs' FFTs done sequentially,
// reusing twiddle staging, window values, and reflect indices.
__global__ __launch_bounds__(256) void stft_mag_kernel(
    const float* __restrict__ x0, const float* __restrict__ x1,
    float* __restrict__ ws, int ch0, int nch)
{
    __shared__ float2 bufA[BUF_SZ];
    __shared__ float2 bufB[BUF_SZ];
    __shared__ float2 tw_s[768];

    const int tid = threadIdx.x;
    const int t   = blockIdx.x;
    const int cg  = blockIdx.y;
    const int ch  = ch0 + cg;

    const float* __restrict__ win = ws + WIN_OFF;
    const float2* __restrict__ twg = (const float2*)(ws + TW_OFF);
    const float2* __restrict__ utw = (const float2*)(ws + UTW_OFF);

    // stage twiddles -> LDS (3/thread, coalesced)
    #pragma unroll
    for (int k = 0; k < 3; ++k) {
        int p = k * 256 + tid;
        tw_s[p] = twg[p];
    }

    // reflect indices + window values, computed once, reused for both inputs
    const int base = t * HOP_ - NFFT / 2;
    int   j0[4], j1[4];
    float wv0[4], wv1[4];
    #pragma unroll
    for (int k = 0; k < 4; ++k) {
        int ci = k * 256 + tid;
        int n0 = 2 * ci, n1 = n0 + 1;
        int a = base + n0;
        a = (a < 0) ? -a : a;
        a = (a >= S_LEN) ? (2 * S_LEN - 2 - a) : a;
        j0[k] = a;
        int b = base + n1;
        b = (b < 0) ? -b : b;
        b = (b >= S_LEN) ? (2 * S_LEN - 2 - b) : b;
        j1[k] = b;
        wv0[k] = win[n0];
        wv1[k] = win[n1];
    }

    for (int which = 0; which < 2; ++which) {
        const float* __restrict__ xin =
            (which == 0 ? x0 : x1) + (size_t)ch * S_LEN;
        float* __restrict__ sout =
            ws + SPEC_OFF
               + ((size_t)which * nch + cg) * (size_t)T_FRAMES * F_BINS
               + (size_t)t * F_BINS;

        // pack even/odd into complex (padded layout)
        #pragma unroll
        for (int k = 0; k < 4; ++k) {
            int ci = k * 256 + tid;
            float re = xin[j0[k]] * wv0[k];
            float im = xin[j1[k]] * wv1[k];
            bufA[phys(ci)] = make_float2(re, im);
        }
        __syncthreads();   // pack done (also orders vs. prev unpack reads of bufB)

        // 5-stage radix-4 Stockham DIF
        float2* A = bufA;
        float2* B = bufB;
        #pragma unroll
        for (int i = 0; i < 5; ++i) {
            const int s_ = 1 << (2 * i);
            const int b  = tid;
            const int q  = b & (s_ - 1);
            const int ps = b - q;            // p * s

            float2 x0c = A[phys(b)];
            float2 x1c = A[phys(b + 256)];
            float2 x2c = A[phys(b + 512)];
            float2 x3c = A[phys(b + 768)];

            float2 t0 = make_float2(x0c.x + x2c.x, x0c.y + x2c.y);
            float2 t1 = make_float2(x0c.x - x2c.x, x0c.y - x2c.y);
            float2 t2 = make_float2(x1c.x + x3c.x, x1c.y + x3c.y);
            float2 t3 = make_float2(x1c.x - x3c.x, x1c.y - x3c.y);

            float2 y0 = make_float2(t0.x + t2.x, t0.y + t2.y);
            float2 y2 = make_float2(t0.x - t2.x, t0.y - t2.y);
            float2 y1 = make_float2(t1.x + t3.y, t1.y - t3.x);   // t1 - i*t3
            float2 y3 = make_float2(t1.x - t3.y, t1.y + t3.x);   // t1 + i*t3

            float2 w1 = tw_s[ps];
            float2 w2 = tw_s[2 * ps];
            float2 w3 = tw_s[3 * ps];

            float2 z1 = make_float2(y1.x * w1.x - y1.y * w1.y, y1.x * w1.y + y1.y * w1.x);
            float2 z2 = make_float2(y2.x * w2.x - y2.y * w2.y, y2.x * w2.y + y2.y * w2.x);
            float2 z3 = make_float2(y3.x * w3.x - y3.y * w3.y, y3.x * w3.y + y3.y * w3.x);

            const int o = q + 4 * ps;
            B[phys(o)]          = y0;
            B[phys(o + s_)]     = z1;
            B[phys(o + 2 * s_)] = z2;
            B[phys(o + 3 * s_)] = z3;
            __syncthreads();
            float2* tmp = A; A = B; B = tmp;
        }

        // unpack real-FFT bins r in [0, 1024], magnitude, store
        for (int r = tid; r < F_BINS; r += 256) {
            float2 Zr = A[phys(r & (NC - 1))];
            float2 Zn = A[phys((NC - r) & (NC - 1))];
            float Ex = 0.5f * (Zr.x + Zn.x);
            float Ey = 0.5f * (Zr.y - Zn.y);
            float Ox = 0.5f * (Zr.y + Zn.y);
            float Oy = 0.5f * (Zn.x - Zr.x);
            float2 wu = utw[r];
            float Xx = Ex + wu.x * Ox - wu.y * Oy;
            float Xy = Ey + wu.x * Oy + wu.y * Ox;
            float m2 = Xx * Xx + Xy * Xy;
            sout[r] = sqrtf(fmaxf(m2, EPS_));
        }
    }
}

// SSIM over interior; rolling vertical sums + software-pipelined row prefetch.
__global__ __launch_bounds__(256) void ssim_kernel(
    const float* __restrict__ ws, float* __restrict__ out,
    int ch0, int nch)
{
    __shared__ float4 cs4[F_BINS];   // (sx, sy, sxx, syy)
    __shared__ float  cs1[F_BINS];   // sxy
    __shared__ double red[256];

    const int tid = threadIdx.x;
    const int cg  = blockIdx.y;
    const int ch  = ch0 + cg;
    const float* __restrict__ spec = ws + SPEC_OFF;
    const float* __restrict__ X = spec + (size_t)cg * (size_t)T_FRAMES * F_BINS;
    const float* __restrict__ Y = spec + ((size_t)nch + cg) * (size_t)T_FRAMES * F_BINS;

    const int t_begin = 3 + blockIdx.x * RPB_;
    const int t_end_  = min(t_begin + RPB_, T_FRAMES - 3); // rows [3, 397]

    const float inv49 = 1.0f / 49.0f;
    double acc = 0.0;

    float sx[5], sy[5], sxx[5], syy[5], sxy[5];
    #pragma unroll
    for (int k = 0; k < 5; ++k) { sx[k]=0.f; sy[k]=0.f; sxx[k]=0.f; syy[k]=0.f; sxy[k]=0.f; }

    // ramp: rows [t_begin-3, t_begin+2]
    for (int r = t_begin - 3; r < t_begin + 3; ++r) {
        #pragma unroll
        for (int k = 0; k < 5; ++k) {
            int f = tid + (k << 8);
            if (f < F_BINS) {
                float xv = X[(size_t)r * F_BINS + f];
                float yv = Y[(size_t)r * F_BINS + f];
                sx[k] += xv; sy[k] += yv;
                sxx[k] += xv * xv; syy[k] += yv * yv; sxy[k] += xv * yv;
            }
        }
    }

    // preload add-row (t+3) and sub-row (t-3) for first iteration
    float pax[5], pay[5], psx[5], psy[5];
    #pragma unroll
    for (int k = 0; k < 5; ++k) {
        int f = tid + (k << 8);
        if (f < F_BINS) {
            pax[k] = X[(size_t)(t_begin + 3) * F_BINS + f];
            pay[k] = Y[(size_t)(t_begin + 3) * F_BINS + f];
            psx[k] = X[(size_t)(t_begin - 3) * F_BINS + f];
            psy[k] = Y[(size_t)(t_begin - 3) * F_BINS + f];
        } else { pax[k]=0.f; pay[k]=0.f; psx[k]=0.f; psy[k]=0.f; }
    }

    for (int t = t_begin; t < t_end_; ++t) {
        // add preloaded row t+3, publish sums (rows t-3..t+3)
        #pragma unroll
        for (int k = 0; k < 5; ++k) {
            int f = tid + (k << 8);
            if (f < F_BINS) {
                sx[k] += pax[k]; sy[k] += pay[k];
                sxx[k] += pax[k] * pax[k]; syy[k] += pay[k] * pay[k];
                sxy[k] += pax[k] * pay[k];
                cs4[f] = make_float4(sx[k], sy[k], sxx[k], syy[k]);
                cs1[f] = sxy[k];
            }
        }
        __syncthreads();

        // subtract row t-3 (registers), issue next iteration's loads NOW so the
        // global latency overlaps the horizontal pass below
        #pragma unroll
        for (int k = 0; k < 5; ++k) {
            sx[k] -= psx[k]; sy[k] -= psy[k];
            sxx[k] -= psx[k] * psx[k]; syy[k] -= psy[k] * psy[k];
            sxy[k] -= psx[k] * psy[k];
        }
        if (t + 1 < t_end_) {
            #pragma unroll
            for (int k = 0; k < 5; ++k) {
                int f = tid + (k << 8);
                if (f < F_BINS) {
                    pax[k] = X[(size_t)(t + 4) * F_BINS + f];
                    pay[k] = Y[(size_t)(t + 4) * F_BINS + f];
                    psx[k] = X[(size_t)(t - 2) * F_BINS + f];
                    psy[k] = Y[(size_t)(t - 2) * F_BINS + f];
                }
            }
        }

        // horizontal 7-tap + SSIM formula, cols [3, 1021]
        for (int f = 3 + tid; f <= F_BINS - 4; f += 256) {
            float4 a0 = cs4[f - 3], a1 = cs4[f - 2], a2 = cs4[f - 1], a3 = cs4[f];
            float4 a4 = cs4[f + 1], a5 = cs4[f + 2], a6 = cs4[f + 3];
            float wx  = a0.x + a1.x + a2.x + a3.x + a4.x + a5.x + a6.x;
            float wy  = a0.y + a1.y + a2.y + a3.y + a4.y + a5.y + a6.y;
            float wxx = a0.z + a1.z + a2.z + a3.z + a4.z + a5.z + a6.z;
            float wyy = a0.w + a1.w + a2.w + a3.w + a4.w + a5.w + a6.w;
            float wxy = cs1[f-3] + cs1[f-2] + cs1[f-1] + cs1[f] + cs1[f+1] + cs1[f+2] + cs1[f+3];

            float ux  = wx  * inv49, uy  = wy  * inv49;
            float uxx = wxx * inv49, uyy = wyy * inv49, uxy = wxy * inv49;
            float vx  = COV_NORM_ * (uxx - ux * ux);
            float vy  = COV_NORM_ * (uyy - uy * uy);
            float vxy = COV_NORM_ * (uxy - ux * uy);
            float Sv = ((2.f * ux * uy + C1_) * (2.f * vxy + C2_)) /
                       ((ux * ux + uy * uy + C1_) * (vx + vy + C2_));
            acc += (double)Sv;
        }
        __syncthreads();
    }

    red[tid] = acc;
    __syncthreads();
    for (int off = 128; off > 0; off >>= 1) {
        if (tid < off) red[tid] += red[tid + off];
        __syncthreads();
    }
    if (tid == 0) {
        atomicAdd(&out[ch], (float)(red[0] / (395.0 * 1019.0)));
    }
}

extern "C" void kernel_launch(void* const* d_in, const int* in_sizes, int n_in,
                              void* d_out, int out_size, void* d_ws, size_t ws_size,
                              hipStream_t stream) {
    const float* x0 = (const float*)d_in[0];   // output
    const float* x1 = (const float*)d_in[1];   // target
    float* out = (float*)d_out;
    float* ws  = (float*)d_ws;

    const size_t table_bytes  = (size_t)SPEC_OFF * sizeof(float);
    const size_t per_ch_bytes = (size_t)2 * T_FRAMES * F_BINS * sizeof(float);
    int G = (int)((ws_size - table_bytes) / per_ch_bytes);
    if (G > N_CH) G = N_CH;
    if (G < 1)    G = 1;

    zero_out_kernel<<<dim3(1), dim3(64), 0, stream>>>(out);
    init_tables_kernel<<<dim3(8), dim3(256), 0, stream>>>(ws);

    for (int ch0 = 0; ch0 < N_CH; ch0 += G) {
        const int nch = (N_CH - ch0 < G) ? (N_CH - ch0) : G;

        dim3 g1(T_FRAMES, nch);
        stft_mag_kernel<<<g1, 256, 0, stream>>>(x0, x1, ws, ch0, nch);

        dim3 g2(N_CHUNKS, nch);
        ssim_kernel<<<g2, 256, 0, stream>>>(ws, out, ch0, nch);
    }
}

// Round 4
// 395.911 us; speedup vs baseline: 1.4409x; 1.0401x over previous
//
#include <hip/hip_runtime.h>
#include <math.h>

#ifndef M_PI
#define M_PI 3.14159265358979323846
#endif

constexpr int S_LEN    = 176400;
constexpr int NFFT     = 2048;
constexpr int NC       = 1024;
constexpr int HOP_     = 441;
constexpr int T_FRAMES = 401;
constexpr int F_BINS   = 1025;
constexpr int F_STRIDE = 1028;     // padded row so float4 col accesses are 16B aligned
constexpr int N_CH     = 64;
constexpr float EPS_   = 1e-8f;
constexpr float C1_    = 0.0004f;
constexpr float C2_    = 0.0036f;
constexpr float COV_NORM_ = 49.0f / 48.0f;

// workspace float offsets
constexpr int WINP_OFF = 0;        // float2[1024]  window pairs (w[2c], w[2c+1])
constexpr int TG1_OFF  = 2048;     // float2[16*64] w1024^(L*k1)  [k1][L]
constexpr int TG2_OFF  = 4096;     // float2[16*4]  w64^(n3*k2)   [k2][n3]
constexpr int UTW_OFF  = 4224;     // float2[1025]  exp(-i*pi*r/1024)
constexpr int SPEC_OFF = 6400;
constexpr int RPB_     = 10;
constexpr int N_CHUNKS = 40;

__device__ __forceinline__ float2 cadd(float2 a, float2 b){ return make_float2(a.x+b.x, a.y+b.y); }
__device__ __forceinline__ float2 csub(float2 a, float2 b){ return make_float2(a.x-b.x, a.y-b.y); }
__device__ __forceinline__ float2 cmul(float2 a, float2 b){ return make_float2(a.x*b.x-a.y*b.y, a.x*b.y+a.y*b.x); }
__device__ __forceinline__ float2 mulnegi(float2 v){ return make_float2(v.y, -v.x); }  // -i*v
__device__ __forceinline__ float4 f4add(float4 a, float4 b){ return make_float4(a.x+b.x,a.y+b.y,a.z+b.z,a.w+b.w); }
__device__ __forceinline__ float4 f4sub(float4 a, float4 b){ return make_float4(a.x-b.x,a.y-b.y,a.z-b.z,a.w-b.w); }
__device__ __forceinline__ int phys4(int f){ return f + (f >> 2); }

// w16^e = exp(-2*pi*i*e/16), e = 0..9 (only products a*m2 used)
__device__ __constant__ float2 W16C[10] = {
    { 1.0f, 0.0f},
    { 0.92387953251128674f, -0.38268343236508978f},
    { 0.70710678118654752f, -0.70710678118654752f},
    { 0.38268343236508978f, -0.92387953251128674f},
    { 0.0f, -1.0f},
    {-0.38268343236508978f, -0.92387953251128674f},
    {-0.70710678118654752f, -0.70710678118654752f},
    {-0.92387953251128674f, -0.38268343236508978f},
    {-1.0f, 0.0f},
    {-0.92387953251128674f,  0.38268343236508978f},
};

// 16-pt DFT in registers: r[k] <- sum_n r[n] w16^{nk}  (natural order in/out)
__device__ __forceinline__ void fft16(float2 (&r)[16]) {
    float2 C[4][4];
    #pragma unroll
    for (int m2 = 0; m2 < 4; ++m2) {
        float2 u0 = r[m2], u1 = r[4+m2], u2 = r[8+m2], u3 = r[12+m2];
        float2 t0 = cadd(u0,u2), t1 = csub(u0,u2), t2 = cadd(u1,u3), t3 = csub(u1,u3);
        C[0][m2] = cadd(t0,t2);
        C[1][m2] = cadd(t1, mulnegi(t3));
        C[2][m2] = csub(t0,t2);
        C[3][m2] = csub(t1, mulnegi(t3));
    }
    #pragma unroll
    for (int a = 0; a < 4; ++a) {
        float2 u0 = C[a][0];
        float2 u1 = (a == 0) ? C[a][1] : cmul(C[a][1], W16C[a]);
        float2 u2 = (a == 0) ? C[a][2] : cmul(C[a][2], W16C[2*a]);
        float2 u3 = (a == 0) ? C[a][3] : cmul(C[a][3], W16C[3*a]);
        float2 t0 = cadd(u0,u2), t1 = csub(u0,u2), t2 = cadd(u1,u3), t3 = csub(u1,u3);
        r[a]      = cadd(t0,t2);
        r[a+4]    = cadd(t1, mulnegi(t3));
        r[a+8]    = csub(t0,t2);
        r[a+12]   = csub(t1, mulnegi(t3));
    }
}

// Tables + output zeroing (runs every call; out zero must precede ssim atomics)
__global__ __launch_bounds__(256) void init_tables_kernel(float* __restrict__ ws, float* __restrict__ out) {
    const int idx = blockIdx.x * 256 + threadIdx.x;
    if (idx < 64) out[idx] = 0.0f;
    if (idx < 1024) {  // window pairs
        float w0 = 0.5f - 0.5f * cosf((float)(2.0 * M_PI / NFFT) * (float)(2*idx));
        float w1 = 0.5f - 0.5f * cosf((float)(2.0 * M_PI / NFFT) * (float)(2*idx+1));
        ws[WINP_OFF + 2*idx]   = w0;
        ws[WINP_OFF + 2*idx+1] = w1;
    }
    if (idx < 1024) {  // tg1[k1*64+L] = exp(-2 pi i L k1 / 1024)
        int k1 = idx >> 6, L = idx & 63;
        float ang = -2.0f * (float)M_PI * (float)(L * k1) / (float)NC;
        float s, c; sincosf(ang, &s, &c);
        ws[TG1_OFF + 2*idx] = c; ws[TG1_OFF + 2*idx+1] = s;
    }
    if (idx < 64) {    // tg2[k2*4+n3] = exp(-2 pi i n3 k2 / 64)
        int k2 = idx >> 2, n3 = idx & 3;
        float ang = -2.0f * (float)M_PI * (float)(n3 * k2) / 64.0f;
        float s, c; sincosf(ang, &s, &c);
        ws[TG2_OFF + 2*idx] = c; ws[TG2_OFF + 2*idx+1] = s;
    }
    if (idx < F_BINS) {
        float ang = -(float)M_PI * (float)idx / (float)NC;
        float s, c; sincosf(ang, &s, &c);
        ws[UTW_OFF + 2*idx] = c; ws[UTW_OFF + 2*idx+1] = s;
    }
}

// One WAVE per 1024-pt FFT (16 complex per lane), 4 waves/block = 2 frames x 2 inputs.
// Factorization 1024 = 16 x 16 x 4; stage-1 comb loaded straight from global.
__global__ __launch_bounds__(256) void stft_mag_kernel(
    const float* __restrict__ x0, const float* __restrict__ x1,
    float* __restrict__ ws, int ch0, int nch, int swizzle)
{
    __shared__ float2 lds[4][1024];

    const int tid  = threadIdx.x;
    const int wave = tid >> 6;
    const int L    = tid & 63;

    int ch, pair;
    if (swizzle) {
        int g = blockIdx.x;
        int xcd = g & 7;
        int s = g >> 3;
        int cl = s & 7;
        pair = s >> 3;                  // [0,201)
        ch = ch0 + xcd * 8 + cl;
    } else {
        pair = blockIdx.x;
        ch = ch0 + blockIdx.y;
    }
    const int which = wave >> 1;
    int t = 2 * pair + (wave & 1);
    const bool store_ok = (t <= 400);
    if (t > 400) t = 400;

    const float* __restrict__ xin = (which ? x1 : x0) + (size_t)ch * S_LEN;
    const float2* __restrict__ winp = (const float2*)(ws + WINP_OFF);
    const float2* __restrict__ tg1  = (const float2*)(ws + TG1_OFF);
    const float2* __restrict__ tg2  = (const float2*)(ws + TG2_OFF);
    const float2* __restrict__ utw  = (const float2*)(ws + UTW_OFF);
    float2* B = lds[wave];

    // ---- load comb + window: r[n1] = (x[2c]w[2c], x[2c+1]w[2c+1]), c = 64*n1 + L
    float2 r[16];
    const int base = t * HOP_ - 1024;
    #pragma unroll
    for (int j = 0; j < 16; ++j) {
        const int s0 = base + 128 * j;           // wave-uniform span start
        const int i0 = s0 + 2 * L;
        float2 wp = winp[(j << 6) + L];
        float a, b;
        if (s0 >= 0 && s0 + 128 <= S_LEN) {      // uniform fast path
            a = xin[i0]; b = xin[i0 + 1];
        } else {
            int ia = i0;     ia = (ia < 0) ? -ia : ia; ia = (ia >= S_LEN) ? 2*S_LEN-2-ia : ia;
            int ib = i0 + 1; ib = (ib < 0) ? -ib : ib; ib = (ib >= S_LEN) ? 2*S_LEN-2-ib : ib;
            a = xin[ia]; b = xin[ib];
        }
        r[j] = make_float2(a * wp.x, b * wp.y);
    }

    // ---- stage 1: 16-pt DFT over n1 + twiddle w1024^{L*k1}; XOR-swizzled store
    fft16(r);
    #pragma unroll
    for (int k1 = 0; k1 < 16; ++k1) {
        float2 v = (k1 == 0) ? r[0] : cmul(r[k1], tg1[(k1 << 6) + L]);
        B[(L << 4) + (k1 ^ (L & 15))] = v;
    }
    __syncthreads();

    // ---- stage 2: thread (k1 = L&15, n3 = L>>4); DFT over n2 + twiddle w64^{n3*k2}
    {
        const int k1 = L & 15, n3 = L >> 4;
        float2 s[16];
        #pragma unroll
        for (int n2 = 0; n2 < 16; ++n2) {
            int lr = (n2 << 2) + n3;
            s[n2] = B[(lr << 4) + (k1 ^ (lr & 15))];
        }
        fft16(s);
        #pragma unroll
        for (int k2 = 1; k2 < 16; ++k2) s[k2] = cmul(s[k2], tg2[(k2 << 2) + n3]);
        __syncthreads();
        #pragma unroll
        for (int k2 = 0; k2 < 16; ++k2) B[(k2 << 6) + L] = s[k2];
    }
    __syncthreads();

    // ---- stage 3: thread (k1b = L&15, g4 = L>>4) holds k2 = 4*g4+r; 4-pt over n3
    {
        const int g4 = L >> 4, k1b = L & 15;
        float2 D[4][4];
        #pragma unroll
        for (int rr = 0; rr < 4; ++rr)
            #pragma unroll
            for (int n3 = 0; n3 < 4; ++n3)
                D[rr][n3] = B[(g4 << 8) + (rr << 6) + (n3 << 4) + k1b];
        __syncthreads();
        #pragma unroll
        for (int rr = 0; rr < 4; ++rr) {
            float2 e0 = cadd(D[rr][0], D[rr][2]);
            float2 e1 = csub(D[rr][0], D[rr][2]);
            float2 e2 = cadd(D[rr][1], D[rr][3]);
            float2 e3 = csub(D[rr][1], D[rr][3]);
            int kb = k1b + (g4 << 6) + (rr << 4);
            B[kb]       = cadd(e0, e2);
            B[kb + 256] = cadd(e1, mulnegi(e3));
            B[kb + 512] = csub(e0, e2);
            B[kb + 768] = csub(e1, mulnegi(e3));
        }
    }
    __syncthreads();

    // ---- real-FFT unpack + magnitude + store
    if (store_ok) {
        float* __restrict__ sout =
            ws + SPEC_OFF + ((size_t)which * nch + (size_t)(ch - ch0)) * (size_t)T_FRAMES * F_STRIDE
                          + (size_t)t * F_STRIDE;
        #pragma unroll
        for (int j = 0; j < 17; ++j) {
            int m = (j << 6) + L;
            if (m <= 1024) {
                float2 Zr = B[m & 1023];
                float2 Zn = B[(1024 - m) & 1023];
                float Ex = 0.5f * (Zr.x + Zn.x);
                float Ey = 0.5f * (Zr.y - Zn.y);
                float Ox = 0.5f * (Zr.y + Zn.y);
                float Oy = 0.5f * (Zn.x - Zr.x);
                float2 wu = utw[m];
                float Xx = Ex + wu.x * Ox - wu.y * Oy;
                float Xy = Ey + wu.x * Oy + wu.y * Ox;
                sout[m] = sqrtf(fmaxf(Xx * Xx + Xy * Xy, EPS_));
            }
        }
    }
}

// SSIM: thread owns 4 consecutive cols; float4 global loads; rolling vertical sums;
// float4 LDS publish (phys4 pad) + rolling horizontal 7-tap.
__global__ __launch_bounds__(256) void ssim_kernel(
    const float* __restrict__ ws, float* __restrict__ out,
    int ch0, int nch)
{
    __shared__ float4 cs4[1296];   // (sx, sy, sxx, syy), phys4-padded
    __shared__ float  cs1[1296];   // sxy
    __shared__ double red[256];

    const int tid = threadIdx.x;
    const int cg  = blockIdx.y;
    const int ch  = ch0 + cg;
    const float* __restrict__ spec = ws + SPEC_OFF;
    const size_t per_ch = (size_t)T_FRAMES * F_STRIDE;
    const float* __restrict__ X = spec + (size_t)cg * per_ch;
    const float* __restrict__ Y = spec + ((size_t)nch + cg) * per_ch;

    const int t_begin = 3 + blockIdx.x * RPB_;
    const int t_end_  = min(t_begin + RPB_, T_FRAMES - 3);

    const int fv = tid << 2;            // vertical cols fv..fv+3
    const bool last = (tid == 255);
    const float inv49 = 1.0f / 49.0f;
    double acc = 0.0;

    float sx[4] = {0,0,0,0}, sy[4] = {0,0,0,0}, sxx[4] = {0,0,0,0},
          syy[4] = {0,0,0,0}, sxy[4] = {0,0,0,0};
    float s5[5] = {0,0,0,0,0};          // col 1024 (tid 255 only)

    // ramp rows [t_begin-3, t_begin+2]
    for (int rr = t_begin - 3; rr < t_begin + 3; ++rr) {
        float4 xv = *(const float4*)(X + (size_t)rr * F_STRIDE + fv);
        float4 yv = *(const float4*)(Y + (size_t)rr * F_STRIDE + fv);
        float xa[4] = {xv.x, xv.y, xv.z, xv.w}, ya[4] = {yv.x, yv.y, yv.z, yv.w};
        #pragma unroll
        for (int c = 0; c < 4; ++c) {
            sx[c] += xa[c]; sy[c] += ya[c];
            sxx[c] += xa[c]*xa[c]; syy[c] += ya[c]*ya[c]; sxy[c] += xa[c]*ya[c];
        }
        if (last) {
            float xe = X[(size_t)rr * F_STRIDE + 1024];
            float ye = Y[(size_t)rr * F_STRIDE + 1024];
            s5[0] += xe; s5[1] += ye; s5[2] += xe*xe; s5[3] += ye*ye; s5[4] += xe*ye;
        }
    }

    // prefetch add-row (t_begin+3) and sub-row (t_begin-3)
    float4 ax, ay, bx, by; float a5x=0, a5y=0, b5x=0, b5y=0;
    ax = *(const float4*)(X + (size_t)(t_begin + 3) * F_STRIDE + fv);
    ay = *(const float4*)(Y + (size_t)(t_begin + 3) * F_STRIDE + fv);
    bx = *(const float4*)(X + (size_t)(t_begin - 3) * F_STRIDE + fv);
    by = *(const float4*)(Y + (size_t)(t_begin - 3) * F_STRIDE + fv);
    if (last) {
        a5x = X[(size_t)(t_begin + 3) * F_STRIDE + 1024];
        a5y = Y[(size_t)(t_begin + 3) * F_STRIDE + 1024];
        b5x = X[(size_t)(t_begin - 3) * F_STRIDE + 1024];
        b5y = Y[(size_t)(t_begin - 3) * F_STRIDE + 1024];
    }

    const int hb = 5 * tid;             // phys4(4*tid)
    const int fo = 3 + (tid << 2);      // first output col

    for (int t = t_begin; t < t_end_; ++t) {
        // add row t+3, publish
        {
            float xa[4] = {ax.x, ax.y, ax.z, ax.w}, ya[4] = {ay.x, ay.y, ay.z, ay.w};
            #pragma unroll
            for (int c = 0; c < 4; ++c) {
                sx[c] += xa[c]; sy[c] += ya[c];
                sxx[c] += xa[c]*xa[c]; syy[c] += ya[c]*ya[c]; sxy[c] += xa[c]*ya[c];
                int p = phys4(fv + c);
                cs4[p] = make_float4(sx[c], sy[c], sxx[c], syy[c]);
                cs1[p] = sxy[c];
            }
            if (last) {
                s5[0] += a5x; s5[1] += a5y; s5[2] += a5x*a5x; s5[3] += a5y*a5y; s5[4] += a5x*a5y;
                int p = phys4(1024);
                cs4[p] = make_float4(s5[0], s5[1], s5[2], s5[3]);
                cs1[p] = s5[4];
            }
        }
        __syncthreads();

        // subtract row t-3 (registers) and prefetch next rows
        {
            float xa[4] = {bx.x, bx.y, bx.z, bx.w}, ya[4] = {by.x, by.y, by.z, by.w};
            #pragma unroll
            for (int c = 0; c < 4; ++c) {
                sx[c] -= xa[c]; sy[c] -= ya[c];
                sxx[c] -= xa[c]*xa[c]; syy[c] -= ya[c]*ya[c]; sxy[c] -= xa[c]*ya[c];
            }
            if (last) {
                s5[0] -= b5x; s5[1] -= b5y; s5[2] -= b5x*b5x; s5[3] -= b5y*b5y; s5[4] -= b5x*b5y;
            }
        }
        if (t + 1 < t_end_) {
            ax = *(const float4*)(X + (size_t)(t + 4) * F_STRIDE + fv);
            ay = *(const float4*)(Y + (size_t)(t + 4) * F_STRIDE + fv);
            bx = *(const float4*)(X + (size_t)(t - 2) * F_STRIDE + fv);
            by = *(const float4*)(Y + (size_t)(t - 2) * F_STRIDE + fv);
            if (last) {
                a5x = X[(size_t)(t + 4) * F_STRIDE + 1024];
                a5y = Y[(size_t)(t + 4) * F_STRIDE + 1024];
                b5x = X[(size_t)(t - 2) * F_STRIDE + 1024];
                b5y = Y[(size_t)(t - 2) * F_STRIDE + 1024];
            }
        }

        // horizontal: 10 taps -> rolling 7-window over 4 output cols
        if (tid < 255) {
            float4 a[10]; float b[10];
            #pragma unroll
            for (int d = 0; d < 10; ++d) {
                int p = hb + d + (d >> 2);     // phys4(4*tid + d), lane-uniform offset
                a[d] = cs4[p];
                b[d] = cs1[p];
            }
            float4 w4 = f4add(f4add(f4add(a[0], a[1]), f4add(a[2], a[3])),
                              f4add(f4add(a[4], a[5]), a[6]));
            float  w1 = b[0]+b[1]+b[2]+b[3]+b[4]+b[5]+b[6];
            #pragma unroll
            for (int c = 0; c < 4; ++c) {
                if (fo + c <= 1021) {
                    float ux  = w4.x * inv49, uy  = w4.y * inv49;
                    float uxx = w4.z * inv49, uyy = w4.w * inv49, uxy = w1 * inv49;
                    float vx  = COV_NORM_ * (uxx - ux * ux);
                    float vy  = COV_NORM_ * (uyy - uy * uy);
                    float vxy = COV_NORM_ * (uxy - ux * uy);
                    float Sv = ((2.f * ux * uy + C1_) * (2.f * vxy + C2_)) /
                               ((ux * ux + uy * uy + C1_) * (vx + vy + C2_));
                    acc += (double)Sv;
                }
                if (c < 3) {
                    w4 = f4add(f4sub(w4, a[c]), a[c + 7]);
                    w1 += b[c + 7] - b[c];
                }
            }
        }
        __syncthreads();
    }

    red[tid] = acc;
    __syncthreads();
    for (int off = 128; off > 0; off >>= 1) {
        if (tid < off) red[tid] += red[tid + off];
        __syncthreads();
    }
    if (tid == 0) {
        atomicAdd(&out[ch], (float)(red[0] / (395.0 * 1019.0)));
    }
}

extern "C" void kernel_launch(void* const* d_in, const int* in_sizes, int n_in,
                              void* d_out, int out_size, void* d_ws, size_t ws_size,
                              hipStream_t stream) {
    const float* x0 = (const float*)d_in[0];   // output
    const float* x1 = (const float*)d_in[1];   // target
    float* out = (float*)d_out;
    float* ws  = (float*)d_ws;

    const size_t table_bytes  = (size_t)SPEC_OFF * sizeof(float);
    const size_t per_ch_bytes = (size_t)2 * T_FRAMES * F_STRIDE * sizeof(float);
    int G = (int)((ws_size - table_bytes) / per_ch_bytes);
    if (G > N_CH) G = N_CH;
    if (G < 1)    G = 1;

    init_tables_kernel<<<dim3(16), dim3(256), 0, stream>>>(ws, out);

    for (int ch0 = 0; ch0 < N_CH; ch0 += G) {
        const int nch = (N_CH - ch0 < G) ? (N_CH - ch0) : G;

        if (nch == 64) {
            stft_mag_kernel<<<dim3(201 * 64), dim3(256), 0, stream>>>(x0, x1, ws, ch0, nch, 1);
        } else {
            stft_mag_kernel<<<dim3(201, nch), dim3(256), 0, stream>>>(x0, x1, ws, ch0, nch, 0);
        }

        dim3 g2(N_CHUNKS, nch);
        ssim_kernel<<<g2, 256, 0, stream>>>(ws, out, ch0, nch);
    }
}

// Round 5
// 395.669 us; speedup vs baseline: 1.4418x; 1.0006x over previous
//
#include <hip/hip_runtime.h>
#include <math.h>

#ifndef M_PI
#define M_PI 3.14159265358979323846
#endif

constexpr int S_LEN    = 176400;
constexpr int NFFT     = 2048;
constexpr int NC       = 1024;
constexpr int HOP_     = 441;
constexpr int T_FRAMES = 401;
constexpr int F_BINS   = 1025;
constexpr int F_STRIDE = 1028;     // padded row so float4 col accesses are 16B aligned
constexpr int N_CH     = 64;
constexpr float EPS_   = 1e-8f;
constexpr float C1_    = 0.0004f;
constexpr float C2_    = 0.0036f;
constexpr float COV_NORM_ = 49.0f / 48.0f;

// workspace float offsets
constexpr int WINP_OFF = 0;        // float2[1024]  window pairs (w[2c], w[2c+1])
constexpr int TG1_OFF  = 2048;     // float2[16*64] w1024^(L*k1)  [k1][L]
constexpr int TG2_OFF  = 4096;     // float2[16*4]  w64^(n3*k2)   [k2][n3]
constexpr int UTW_OFF  = 4224;     // float2[1025]  exp(-i*pi*r/1024)
constexpr int SPEC_OFF = 6400;
constexpr int RPB_     = 10;
constexpr int N_CHUNKS = 40;

// wave-local ordering fence: LDS traffic in stft is strictly intra-wave, so a
// full block barrier (s_barrier + vmcnt drain) is unnecessary — lgkmcnt(0)
// guarantees this wave's DS ops completed; "memory" stops compiler reordering.
#define WAVE_SYNC() asm volatile("s_waitcnt lgkmcnt(0)" ::: "memory")

__device__ __forceinline__ float2 cadd(float2 a, float2 b){ return make_float2(a.x+b.x, a.y+b.y); }
__device__ __forceinline__ float2 csub(float2 a, float2 b){ return make_float2(a.x-b.x, a.y-b.y); }
__device__ __forceinline__ float2 cmul(float2 a, float2 b){ return make_float2(a.x*b.x-a.y*b.y, a.x*b.y+a.y*b.x); }
__device__ __forceinline__ float2 mulnegi(float2 v){ return make_float2(v.y, -v.x); }  // -i*v

// w16^e = exp(-2*pi*i*e/16), e = 0..9 (only products a*m2 used)
__device__ __constant__ float2 W16C[10] = {
    { 1.0f, 0.0f},
    { 0.92387953251128674f, -0.38268343236508978f},
    { 0.70710678118654752f, -0.70710678118654752f},
    { 0.38268343236508978f, -0.92387953251128674f},
    { 0.0f, -1.0f},
    {-0.38268343236508978f, -0.92387953251128674f},
    {-0.70710678118654752f, -0.70710678118654752f},
    {-0.92387953251128674f, -0.38268343236508978f},
    {-1.0f, 0.0f},
    {-0.92387953251128674f,  0.38268343236508978f},
};

// 16-pt DFT in registers: r[k] <- sum_n r[n] w16^{nk}  (natural order in/out)
__device__ __forceinline__ void fft16(float2 (&r)[16]) {
    float2 C[4][4];
    #pragma unroll
    for (int m2 = 0; m2 < 4; ++m2) {
        float2 u0 = r[m2], u1 = r[4+m2], u2 = r[8+m2], u3 = r[12+m2];
        float2 t0 = cadd(u0,u2), t1 = csub(u0,u2), t2 = cadd(u1,u3), t3 = csub(u1,u3);
        C[0][m2] = cadd(t0,t2);
        C[1][m2] = cadd(t1, mulnegi(t3));
        C[2][m2] = csub(t0,t2);
        C[3][m2] = csub(t1, mulnegi(t3));
    }
    #pragma unroll
    for (int a = 0; a < 4; ++a) {
        float2 u0 = C[a][0];
        float2 u1 = (a == 0) ? C[a][1] : cmul(C[a][1], W16C[a]);
        float2 u2 = (a == 0) ? C[a][2] : cmul(C[a][2], W16C[2*a]);
        float2 u3 = (a == 0) ? C[a][3] : cmul(C[a][3], W16C[3*a]);
        float2 t0 = cadd(u0,u2), t1 = csub(u0,u2), t2 = cadd(u1,u3), t3 = csub(u1,u3);
        r[a]      = cadd(t0,t2);
        r[a+4]    = cadd(t1, mulnegi(t3));
        r[a+8]    = csub(t0,t2);
        r[a+12]   = csub(t1, mulnegi(t3));
    }
}

// Tables + output zeroing (runs every call; out zero must precede ssim atomics)
__global__ __launch_bounds__(256) void init_tables_kernel(float* __restrict__ ws, float* __restrict__ out) {
    const int idx = blockIdx.x * 256 + threadIdx.x;
    if (idx < 64) out[idx] = 0.0f;
    if (idx < 1024) {  // window pairs
        float w0 = 0.5f - 0.5f * cosf((float)(2.0 * M_PI / NFFT) * (float)(2*idx));
        float w1 = 0.5f - 0.5f * cosf((float)(2.0 * M_PI / NFFT) * (float)(2*idx+1));
        ws[WINP_OFF + 2*idx]   = w0;
        ws[WINP_OFF + 2*idx+1] = w1;
    }
    if (idx < 1024) {  // tg1[k1*64+L] = exp(-2 pi i L k1 / 1024)
        int k1 = idx >> 6, L = idx & 63;
        float ang = -2.0f * (float)M_PI * (float)(L * k1) / (float)NC;
        float s, c; sincosf(ang, &s, &c);
        ws[TG1_OFF + 2*idx] = c; ws[TG1_OFF + 2*idx+1] = s;
    }
    if (idx < 64) {    // tg2[k2*4+n3] = exp(-2 pi i n3 k2 / 64)
        int k2 = idx >> 2, n3 = idx & 3;
        float ang = -2.0f * (float)M_PI * (float)(n3 * k2) / 64.0f;
        float s, c; sincosf(ang, &s, &c);
        ws[TG2_OFF + 2*idx] = c; ws[TG2_OFF + 2*idx+1] = s;
    }
    if (idx < F_BINS) {
        float ang = -(float)M_PI * (float)idx / (float)NC;
        float s, c; sincosf(ang, &s, &c);
        ws[UTW_OFF + 2*idx] = c; ws[UTW_OFF + 2*idx+1] = s;
    }
}

// One WAVE per 1024-pt FFT (16 complex per lane), 4 waves/block, ZERO block barriers.
// Factorization 1024 = 16 x 16 x 4; stage-1 comb loaded straight from global.
__global__ __launch_bounds__(256) void stft_mag_kernel(
    const float* __restrict__ x0, const float* __restrict__ x1,
    float* __restrict__ ws, int ch0, int nch, int swizzle)
{
    __shared__ float2 lds[4][1024];

    const int tid  = threadIdx.x;
    const int wave = tid >> 6;
    const int L    = tid & 63;

    int ch, pair;
    if (swizzle) {
        int g = blockIdx.x;
        int xcd = g & 7;
        int s = g >> 3;
        int cl = s & 7;
        pair = s >> 3;                  // [0,201)
        ch = ch0 + xcd * 8 + cl;
    } else {
        pair = blockIdx.x;
        ch = ch0 + blockIdx.y;
    }
    const int which = wave >> 1;
    const int t = 2 * pair + (wave & 1);
    if (t > 400) return;                // padding wave; no barriers, safe to exit

    const float* __restrict__ xin = (which ? x1 : x0) + (size_t)ch * S_LEN;
    const float2* __restrict__ winp = (const float2*)(ws + WINP_OFF);
    const float2* __restrict__ tg1  = (const float2*)(ws + TG1_OFF);
    const float2* __restrict__ tg2  = (const float2*)(ws + TG2_OFF);
    const float2* __restrict__ utw  = (const float2*)(ws + UTW_OFF);
    float2* B = lds[wave];

    // ---- load comb + window: r[n1] = (x[2c]w[2c], x[2c+1]w[2c+1]), c = 64*n1 + L
    float2 r[16];
    const int base = t * HOP_ - 1024;
    #pragma unroll
    for (int j = 0; j < 16; ++j) {
        const int s0 = base + 128 * j;           // wave-uniform span start
        const int i0 = s0 + 2 * L;
        float2 wp = winp[(j << 6) + L];
        float a, b;
        if (s0 >= 0 && s0 + 128 <= S_LEN) {      // uniform fast path
            a = xin[i0]; b = xin[i0 + 1];
        } else {
            int ia = i0;     ia = (ia < 0) ? -ia : ia; ia = (ia >= S_LEN) ? 2*S_LEN-2-ia : ia;
            int ib = i0 + 1; ib = (ib < 0) ? -ib : ib; ib = (ib >= S_LEN) ? 2*S_LEN-2-ib : ib;
            a = xin[ia]; b = xin[ib];
        }
        r[j] = make_float2(a * wp.x, b * wp.y);
    }

    // ---- stage 1: 16-pt DFT over n1 + twiddle w1024^{L*k1}; XOR-swizzled store
    fft16(r);
    #pragma unroll
    for (int k1 = 0; k1 < 16; ++k1) {
        float2 v = (k1 == 0) ? r[0] : cmul(r[k1], tg1[(k1 << 6) + L]);
        B[(L << 4) + (k1 ^ (L & 15))] = v;
    }
    WAVE_SYNC();

    // ---- stage 2: thread (k1 = L&15, n3 = L>>4); DFT over n2 + twiddle w64^{n3*k2}
    {
        const int k1 = L & 15, n3 = L >> 4;
        float2 s[16];
        #pragma unroll
        for (int n2 = 0; n2 < 16; ++n2) {
            int lr = (n2 << 2) + n3;
            s[n2] = B[(lr << 4) + (k1 ^ (lr & 15))];
        }
        fft16(s);
        #pragma unroll
        for (int k2 = 1; k2 < 16; ++k2) s[k2] = cmul(s[k2], tg2[(k2 << 2) + n3]);
        WAVE_SYNC();
        #pragma unroll
        for (int k2 = 0; k2 < 16; ++k2) B[(k2 << 6) + L] = s[k2];
    }
    WAVE_SYNC();

    // ---- stage 3: thread (k1b = L&15, g4 = L>>4) holds k2 = 4*g4+r; 4-pt over n3
    {
        const int g4 = L >> 4, k1b = L & 15;
        float2 D[4][4];
        #pragma unroll
        for (int rr = 0; rr < 4; ++rr)
            #pragma unroll
            for (int n3 = 0; n3 < 4; ++n3)
                D[rr][n3] = B[(g4 << 8) + (rr << 6) + (n3 << 4) + k1b];
        WAVE_SYNC();
        #pragma unroll
        for (int rr = 0; rr < 4; ++rr) {
            float2 e0 = cadd(D[rr][0], D[rr][2]);
            float2 e1 = csub(D[rr][0], D[rr][2]);
            float2 e2 = cadd(D[rr][1], D[rr][3]);
            float2 e3 = csub(D[rr][1], D[rr][3]);
            int kb = k1b + (g4 << 6) + (rr << 4);
            B[kb]       = cadd(e0, e2);
            B[kb + 256] = cadd(e1, mulnegi(e3));
            B[kb + 512] = csub(e0, e2);
            B[kb + 768] = csub(e1, mulnegi(e3));
        }
    }
    WAVE_SYNC();

    // ---- real-FFT unpack + magnitude + store
    {
        float* __restrict__ sout =
            ws + SPEC_OFF + ((size_t)which * nch + (size_t)(ch - ch0)) * (size_t)T_FRAMES * F_STRIDE
                          + (size_t)t * F_STRIDE;
        #pragma unroll
        for (int j = 0; j < 17; ++j) {
            int m = (j << 6) + L;
            if (j < 16 || L == 0) {
                float2 Zr = B[m & 1023];
                float2 Zn = B[(1024 - m) & 1023];
                float Ex = 0.5f * (Zr.x + Zn.x);
                float Ey = 0.5f * (Zr.y - Zn.y);
                float Ox = 0.5f * (Zr.y + Zn.y);
                float Oy = 0.5f * (Zn.x - Zr.x);
                float2 wu = utw[m];
                float Xx = Ex + wu.x * Ox - wu.y * Oy;
                float Xy = Ey + wu.x * Oy + wu.y * Ox;
                sout[m] = sqrtf(fmaxf(Xx * Xx + Xy * Xy, EPS_));
            }
        }
    }
}

// SSIM: thread owns 4 consecutive cols; float4 global loads; rolling vertical sums;
// 5 scalar LDS arrays with +1/4 pad -> lane stride 5 words, conflict-free.
__global__ __launch_bounds__(256) void ssim_kernel(
    const float* __restrict__ ws, float* __restrict__ out,
    int ch0, int nch)
{
    __shared__ float csx[1284], csy[1284], csxx[1284], csyy[1284], csxy[1284];
    __shared__ double red[256];

    const int tid = threadIdx.x;
    const int cg  = blockIdx.y;
    const int ch  = ch0 + cg;
    const float* __restrict__ spec = ws + SPEC_OFF;
    const size_t per_ch = (size_t)T_FRAMES * F_STRIDE;
    const float* __restrict__ X = spec + (size_t)cg * per_ch;
    const float* __restrict__ Y = spec + ((size_t)nch + cg) * per_ch;

    const int t_begin = 3 + blockIdx.x * RPB_;
    const int t_end_  = min(t_begin + RPB_, T_FRAMES - 3);

    const int fv = tid << 2;            // vertical cols fv..fv+3
    const bool last = (tid == 255);
    const float inv49 = 1.0f / 49.0f;
    double acc = 0.0;

    float sx[4] = {0,0,0,0}, sy[4] = {0,0,0,0}, sxx[4] = {0,0,0,0},
          syy[4] = {0,0,0,0}, sxy[4] = {0,0,0,0};
    float s5[5] = {0,0,0,0,0};          // col 1024 (tid 255 only)

    // ramp rows [t_begin-3, t_begin+2]
    for (int rr = t_begin - 3; rr < t_begin + 3; ++rr) {
        float4 xv = *(const float4*)(X + (size_t)rr * F_STRIDE + fv);
        float4 yv = *(const float4*)(Y + (size_t)rr * F_STRIDE + fv);
        float xa[4] = {xv.x, xv.y, xv.z, xv.w}, ya[4] = {yv.x, yv.y, yv.z, yv.w};
        #pragma unroll
        for (int c = 0; c < 4; ++c) {
            sx[c] += xa[c]; sy[c] += ya[c];
            sxx[c] += xa[c]*xa[c]; syy[c] += ya[c]*ya[c]; sxy[c] += xa[c]*ya[c];
        }
        if (last) {
            float xe = X[(size_t)rr * F_STRIDE + 1024];
            float ye = Y[(size_t)rr * F_STRIDE + 1024];
            s5[0] += xe; s5[1] += ye; s5[2] += xe*xe; s5[3] += ye*ye; s5[4] += xe*ye;
        }
    }

    // prefetch add-row (t_begin+3) and sub-row (t_begin-3)
    float4 ax, ay, bx, by; float a5x=0, a5y=0, b5x=0, b5y=0;
    ax = *(const float4*)(X + (size_t)(t_begin + 3) * F_STRIDE + fv);
    ay = *(const float4*)(Y + (size_t)(t_begin + 3) * F_STRIDE + fv);
    bx = *(const float4*)(X + (size_t)(t_begin - 3) * F_STRIDE + fv);
    by = *(const float4*)(Y + (size_t)(t_begin - 3) * F_STRIDE + fv);
    if (last) {
        a5x = X[(size_t)(t_begin + 3) * F_STRIDE + 1024];
        a5y = Y[(size_t)(t_begin + 3) * F_STRIDE + 1024];
        b5x = X[(size_t)(t_begin - 3) * F_STRIDE + 1024];
        b5y = Y[(size_t)(t_begin - 3) * F_STRIDE + 1024];
    }

    const int fo = 3 + (tid << 2);      // first output col

    for (int t = t_begin; t < t_end_; ++t) {
        // add row t+3, publish (phys4(4*tid+c) == 5*tid+c for c<4)
        {
            float xa[4] = {ax.x, ax.y, ax.z, ax.w}, ya[4] = {ay.x, ay.y, ay.z, ay.w};
            #pragma unroll
            for (int c = 0; c < 4; ++c) {
                sx[c] += xa[c]; sy[c] += ya[c];
                sxx[c] += xa[c]*xa[c]; syy[c] += ya[c]*ya[c]; sxy[c] += xa[c]*ya[c];
                int p = 5 * tid + c;
                csx[p] = sx[c]; csy[p] = sy[c];
                csxx[p] = sxx[c]; csyy[p] = syy[c]; csxy[p] = sxy[c];
            }
            if (last) {
                s5[0] += a5x; s5[1] += a5y; s5[2] += a5x*a5x; s5[3] += a5y*a5y; s5[4] += a5x*a5y;
                csx[1280] = s5[0]; csy[1280] = s5[1];
                csxx[1280] = s5[2]; csyy[1280] = s5[3]; csxy[1280] = s5[4];
            }
        }
        __syncthreads();

        // subtract row t-3 (registers) and prefetch next rows
        {
            float xa[4] = {bx.x, bx.y, bx.z, bx.w}, ya[4] = {by.x, by.y, by.z, by.w};
            #pragma unroll
            for (int c = 0; c < 4; ++c) {
                sx[c] -= xa[c]; sy[c] -= ya[c];
                sxx[c] -= xa[c]*xa[c]; syy[c] -= ya[c]*ya[c]; sxy[c] -= xa[c]*ya[c];
            }
            if (last) {
                s5[0] -= b5x; s5[1] -= b5y; s5[2] -= b5x*b5x; s5[3] -= b5y*b5y; s5[4] -= b5x*b5y;
            }
        }
        if (t + 1 < t_end_) {
            ax = *(const float4*)(X + (size_t)(t + 4) * F_STRIDE + fv);
            ay = *(const float4*)(Y + (size_t)(t + 4) * F_STRIDE + fv);
            bx = *(const float4*)(X + (size_t)(t - 2) * F_STRIDE + fv);
            by = *(const float4*)(Y + (size_t)(t - 2) * F_STRIDE + fv);
            if (last) {
                a5x = X[(size_t)(t + 4) * F_STRIDE + 1024];
                a5y = Y[(size_t)(t + 4) * F_STRIDE + 1024];
                b5x = X[(size_t)(t - 2) * F_STRIDE + 1024];
                b5y = Y[(size_t)(t - 2) * F_STRIDE + 1024];
            }
        }

        // horizontal: 10 taps (lane stride 5 -> conflict-free) -> rolling 7-window
        if (tid < 255) {
            float tx[10], ty[10], txx[10], tyy[10], txy[10];
            #pragma unroll
            for (int d = 0; d < 10; ++d) {
                int p = 5 * tid + d + (d >> 2);    // phys4(4*tid + d)
                tx[d] = csx[p]; ty[d] = csy[p];
                txx[d] = csxx[p]; tyy[d] = csyy[p]; txy[d] = csxy[p];
            }
            float wx  = tx[0]+tx[1]+tx[2]+tx[3]+tx[4]+tx[5]+tx[6];
            float wy  = ty[0]+ty[1]+ty[2]+ty[3]+ty[4]+ty[5]+ty[6];
            float wxx = txx[0]+txx[1]+txx[2]+txx[3]+txx[4]+txx[5]+txx[6];
            float wyy = tyy[0]+tyy[1]+tyy[2]+tyy[3]+tyy[4]+tyy[5]+tyy[6];
            float wxy = txy[0]+txy[1]+txy[2]+txy[3]+txy[4]+txy[5]+txy[6];
            #pragma unroll
            for (int c = 0; c < 4; ++c) {
                if (fo + c <= 1021) {
                    float ux  = wx * inv49, uy  = wy * inv49;
                    float uxx = wxx * inv49, uyy = wyy * inv49, uxy = wxy * inv49;
                    float vx  = COV_NORM_ * (uxx - ux * ux);
                    float vy  = COV_NORM_ * (uyy - uy * uy);
                    float vxy = COV_NORM_ * (uxy - ux * uy);
                    float Sv = ((2.f * ux * uy + C1_) * (2.f * vxy + C2_)) /
                               ((ux * ux + uy * uy + C1_) * (vx + vy + C2_));
                    acc += (double)Sv;
                }
                if (c < 3) {
                    wx  += tx[c+7]  - tx[c];
                    wy  += ty[c+7]  - ty[c];
                    wxx += txx[c+7] - txx[c];
                    wyy += tyy[c+7] - tyy[c];
                    wxy += txy[c+7] - txy[c];
                }
            }
        }
        __syncthreads();
    }

    red[tid] = acc;
    __syncthreads();
    for (int off = 128; off > 0; off >>= 1) {
        if (tid < off) red[tid] += red[tid + off];
        __syncthreads();
    }
    if (tid == 0) {
        atomicAdd(&out[ch], (float)(red[0] / (395.0 * 1019.0)));
    }
}

extern "C" void kernel_launch(void* const* d_in, const int* in_sizes, int n_in,
                              void* d_out, int out_size, void* d_ws, size_t ws_size,
                              hipStream_t stream) {
    const float* x0 = (const float*)d_in[0];   // output
    const float* x1 = (const float*)d_in[1];   // target
    float* out = (float*)d_out;
    float* ws  = (float*)d_ws;

    const size_t table_bytes  = (size_t)SPEC_OFF * sizeof(float);
    const size_t per_ch_bytes = (size_t)2 * T_FRAMES * F_STRIDE * sizeof(float);
    int G = (int)((ws_size - table_bytes) / per_ch_bytes);
    if (G > N_CH) G = N_CH;
    if (G < 1)    G = 1;

    init_tables_kernel<<<dim3(16), dim3(256), 0, stream>>>(ws, out);

    for (int ch0 = 0; ch0 < N_CH; ch0 += G) {
        const int nch = (N_CH - ch0 < G) ? (N_CH - ch0) : G;

        if (nch == 64) {
            stft_mag_kernel<<<dim3(201 * 64), dim3(256), 0, stream>>>(x0, x1, ws, ch0, nch, 1);
        } else {
            stft_mag_kernel<<<dim3(201, nch), dim3(256), 0, stream>>>(x0, x1, ws, ch0, nch, 0);
        }

        dim3 g2(N_CHUNKS, nch);
        ssim_kernel<<<g2, 256, 0, stream>>>(ws, out, ch0, nch);
    }
}